// Round 2
// baseline (278.733 us; speedup 1.0000x reference)
//
#include <hip/hip_runtime.h>
#include <hip/hip_bf16.h>

typedef __attribute__((ext_vector_type(8))) short bf16x8;
typedef __attribute__((ext_vector_type(4))) short short4v;
typedef __attribute__((ext_vector_type(4))) float f32x4;
typedef unsigned int u32;

// ---------- helpers ----------
__device__ __forceinline__ short f2bf(float f) {
    union { float f; u32 i; } c; c.f = f;
    u32 r = c.i + 0x7FFFu + ((c.i >> 16) & 1u);   // RNE
    return (short)(r >> 16);
}
__device__ __forceinline__ u32 pack2bf(float lo, float hi) {
    return ((u32)(unsigned short)f2bf(hi) << 16) | (u32)(unsigned short)f2bf(lo);
}
__device__ __forceinline__ f32x4 mfma16(bf16x8 a, bf16x8 b, f32x4 c) {
    return __builtin_amdgcn_mfma_f32_16x16x32_bf16(a, b, c, 0, 0, 0);
}
__device__ __forceinline__ void load_lds16(const void* g, void* l) {
    __builtin_amdgcn_global_load_lds(
        (const __attribute__((address_space(1))) u32*)g,
        (__attribute__((address_space(3))) u32*)l, 16, 0, 0);
}

// ---------- fp32 -> bf16 convert (x + 4 weights fused) ----------
__global__ __launch_bounds__(256) void cvt_all_kernel(
    const float* __restrict__ x, const float* __restrict__ wq,
    const float* __restrict__ wk, const float* __restrict__ wv,
    const float* __restrict__ wo, short* __restrict__ ws) {
    const int XV = (4096 * 1024) / 4;   // float4 count for x
    const int WV = (1024 * 1024) / 4;   // float4 count per weight
    int i = blockIdx.x * 256 + threadIdx.x;
    const float4* src; short4v* dst; int off;
    if (i < XV)            { src = (const float4*)x;  dst = (short4v*)(ws);           off = i; }
    else if (i < XV + WV)  { src = (const float4*)wq; dst = (short4v*)(ws + 4194304); off = i - XV; }
    else if (i < XV + 2*WV){ src = (const float4*)wk; dst = (short4v*)(ws + 5242880); off = i - XV - WV; }
    else if (i < XV + 3*WV){ src = (const float4*)wv; dst = (short4v*)(ws + 6291456); off = i - XV - 2*WV; }
    else                   { src = (const float4*)wo; dst = (short4v*)(ws + 7340032); off = i - XV - 3*WV; }
    float4 v = src[off];
    short4v o;
    o.x = f2bf(v.x); o.y = f2bf(v.y); o.z = f2bf(v.z); o.w = f2bf(v.w);
    dst[off] = o;
}

// ---------- shared GEMM mainloop: C[128x128] += A[128xK] * B[128xK]^T ----------
__device__ __forceinline__ void gemm_mainloop(
    const short* __restrict__ A, const short* __restrict__ Bm,
    short* lds, int mbase, int nbase, int wave, int lane, f32x4 acc[4][4]) {
    const int K = 1024;
    const int lr = lane & 15, lg = lane >> 4;
    const int wm = wave >> 1, wn = wave & 1;
    for (int k0 = 0; k0 < K; k0 += 64) {
        __syncthreads();
        #pragma unroll
        for (int issue = 0; issue < 4; ++issue) {
            int f = issue * 4 + wave;
            int mt = f >> 1, kc = f & 1;
            load_lds16(A  + (size_t)(mbase + mt*16 + lr)*K + (k0 + kc*32 + lg*8), lds + f*512);
            load_lds16(Bm + (size_t)(nbase + mt*16 + lr)*K + (k0 + kc*32 + lg*8), lds + 8192 + f*512);
        }
        __syncthreads();
        #pragma unroll
        for (int kc = 0; kc < 2; ++kc) {
            bf16x8 af[4], bfv[4];
            #pragma unroll
            for (int mi = 0; mi < 4; ++mi)
                af[mi] = *(const bf16x8*)(lds + ((wm*4 + mi)*2 + kc)*512 + lane*8);
            #pragma unroll
            for (int ni = 0; ni < 4; ++ni)
                bfv[ni] = *(const bf16x8*)(lds + 8192 + ((wn*4 + ni)*2 + kc)*512 + lane*8);
            #pragma unroll
            for (int mi = 0; mi < 4; ++mi)
                #pragma unroll
                for (int ni = 0; ni < 4; ++ni)
                    acc[mi][ni] = mfma16(af[mi], bfv[ni], acc[mi][ni]);
        }
    }
}

// ---------- fused QKV projection ----------
__global__ __launch_bounds__(256) void gemm_qkv_kernel(
    const short* __restrict__ xb, const short* __restrict__ wqb,
    const short* __restrict__ wkb, const short* __restrict__ wvb,
    short* __restrict__ Qh, short* __restrict__ Kh, short* __restrict__ Vt) {
    __shared__ short lds[16384];
    const int wave = threadIdx.x >> 6, lane = threadIdx.x & 63;
    const int lr = lane & 15, lg = lane >> 4;
    const int sel = blockIdx.x >> 3;
    const int nbase = (blockIdx.x & 7) * 128;
    const int mbase = blockIdx.y * 128;
    const short* Bm = (sel == 0) ? wqb : (sel == 1) ? wkb : wvb;

    f32x4 acc[4][4];
    #pragma unroll
    for (int i = 0; i < 4; ++i)
        #pragma unroll
        for (int j = 0; j < 4; ++j) acc[i][j] = f32x4{0.f, 0.f, 0.f, 0.f};

    gemm_mainloop(xb, Bm, lds, mbase, nbase, wave, lane, acc);

    const int wm = wave >> 1, wn = wave & 1;
    #pragma unroll
    for (int mi = 0; mi < 4; ++mi) {
        int m0 = mbase + wm*64 + mi*16 + lg*4;
        #pragma unroll
        for (int ni = 0; ni < 4; ++ni) {
            int nc = nbase + wn*64 + ni*16 + lr;
            int h = nc >> 6, d = nc & 63;
            f32x4 v = acc[mi][ni];
            if (sel == 2) {
                int bi = m0 >> 11, np = m0 & 2047;
                short4v o;
                o.x = f2bf(v.x); o.y = f2bf(v.y); o.z = f2bf(v.z); o.w = f2bf(v.w);
                *(short4v*)&Vt[((size_t)(bi*16 + h)*64 + d)*2048 + np] = o;
            } else {
                short* dstb = (sel == 0) ? Qh : Kh;
                float sc = (sel == 0) ? 0.125f : 1.0f;
                #pragma unroll
                for (int r = 0; r < 4; ++r) {
                    int m = m0 + r; int bi = m >> 11, np = m & 2047;
                    dstb[((size_t)(bi*16 + h)*2048 + np)*64 + d] = f2bf(v[r] * sc);
                }
            }
        }
    }
}

// ---------- output projection ----------
__global__ __launch_bounds__(256) void gemm_out_kernel(
    const short* __restrict__ AO, const short* __restrict__ wob,
    const float* __restrict__ bias, float* __restrict__ out) {
    __shared__ short lds[16384];
    const int wave = threadIdx.x >> 6, lane = threadIdx.x & 63;
    const int lr = lane & 15, lg = lane >> 4;
    const int nbase = blockIdx.x * 128;
    const int mbase = blockIdx.y * 128;

    f32x4 acc[4][4];
    #pragma unroll
    for (int i = 0; i < 4; ++i)
        #pragma unroll
        for (int j = 0; j < 4; ++j) acc[i][j] = f32x4{0.f, 0.f, 0.f, 0.f};

    gemm_mainloop(AO, wob, lds, mbase, nbase, wave, lane, acc);

    const int wm = wave >> 1, wn = wave & 1;
    #pragma unroll
    for (int mi = 0; mi < 4; ++mi) {
        int m0 = mbase + wm*64 + mi*16 + lg*4;
        #pragma unroll
        for (int ni = 0; ni < 4; ++ni) {
            int nc = nbase + wn*64 + ni*16 + lr;
            float bj = bias[nc];
            f32x4 v = acc[mi][ni];
            #pragma unroll
            for (int r = 0; r < 4; ++r)
                out[(size_t)(m0 + r)*1024 + nc] = v[r] + bj;
        }
    }
}

// ---------- balanced flash-style 2-pass adaptive-temperature attention ----------
// 2048 equal-work wave-tasks: wave W = (bh, p); it processes 16-row q-group
// g = p then g = 127-p sequentially (chunk counts sum to a constant), so every
// wave runs the same duration -> no causal straggler tail. Swapped QK^T per
// 16-row group; interior chunks are mask-free.
__global__ __launch_bounds__(256) void attn_kernel(
    const short* __restrict__ Qh, const short* __restrict__ Kh,
    const short* __restrict__ Vt, short* __restrict__ AO) {
    const int lane = threadIdx.x & 63;
    const int wave = threadIdx.x >> 6;
    const int W  = blockIdx.x * 4 + wave;    // 0..2047
    const int bh = W >> 6;                   // 64 pairs per (b,h)
    const int p  = W & 63;
    const int lr = lane & 15, lg = lane >> 4;
    const short* Q = Qh + (size_t)bh * (2048 * 64);
    const short* K = Kh + (size_t)bh * (2048 * 64);
    const short* V = Vt + (size_t)bh * (64 * 2048);
    const int b = bh >> 4, h = bh & 15;

    #pragma unroll 1
    for (int gi = 0; gi < 2; ++gi) {
        const int g  = gi ? (127 - p) : p;   // 16-row q-group index
        const int qa = g * 16 + lr;

        bf16x8 qf0 = *(const bf16x8*)&Q[(size_t)qa*64 + lg*8];
        bf16x8 qf1 = *(const bf16x8*)&Q[(size_t)qa*64 + 32 + lg*8];

        // ---- pass 1: entropy stats (ref-max 0; logits O(1)) ----
        float s = 0.f, t = 0.f;
        #pragma unroll 1
        for (int kt = 0; kt < g; ++kt) {     // interior chunks: no mask
            const short* Kr = &K[(size_t)(kt*16 + lr)*64 + lg*8];
            bf16x8 kf0 = *(const bf16x8*)Kr;
            bf16x8 kf1 = *(const bf16x8*)(Kr + 32);
            f32x4 d = {0.f,0.f,0.f,0.f};
            d = mfma16(kf0, qf0, d); d = mfma16(kf1, qf1, d);
            #pragma unroll
            for (int r = 0; r < 4; ++r) {
                float e = __expf(d[r]); s += e; t += e * d[r];
            }
        }
        {   // boundary chunk kt == g (masked)
            const short* Kr = &K[(size_t)(g*16 + lr)*64 + lg*8];
            bf16x8 kf0 = *(const bf16x8*)Kr;
            bf16x8 kf1 = *(const bf16x8*)(Kr + 32);
            f32x4 d = {0.f,0.f,0.f,0.f};
            d = mfma16(kf0, qf0, d); d = mfma16(kf1, qf1, d);
            int kb = g*16 + lg*4;
            #pragma unroll
            for (int r = 0; r < 4; ++r) {
                float l = (kb + r <= qa) ? d[r] : -1e30f;
                float e = __expf(l); s += e; t += e * l;
            }
        }
        s += __shfl_xor(s, 16); t += __shfl_xor(t, 16);
        s += __shfl_xor(s, 32); t += __shfl_xor(t, 32);
        float H = __logf(s) - t / s;
        float beta = 1.f;
        if (H > 0.5f)
            beta = fmaxf((((-0.037f*H + 0.481f)*H - 2.3f)*H + 4.917f)*H - 1.791f, 1.f);

        // ---- pass 2: softmax(beta*l) and PV ----
        f32x4 o[4];
        #pragma unroll
        for (int dc = 0; dc < 4; ++dc) o[dc] = f32x4{0.f,0.f,0.f,0.f};
        float s2 = 0.f;
        const int nfull = g >> 1;            // fully-unmasked 32-k chunks
        #pragma unroll 1
        for (int ch = 0; ch <= nfull; ++ch) {
            u32 pk[2][2];
            const bool full = (ch < nfull);
            #pragma unroll
            for (int tt = 0; tt < 2; ++tt) {
                int kt = ch*2 + tt;
                const short* Kr = &K[(size_t)(kt*16 + lr)*64 + lg*8];
                bf16x8 kf0 = *(const bf16x8*)Kr;
                bf16x8 kf1 = *(const bf16x8*)(Kr + 32);
                f32x4 d = {0.f,0.f,0.f,0.f};
                d = mfma16(kf0, qf0, d); d = mfma16(kf1, qf1, d);
                float pv[4];
                if (full) {
                    #pragma unroll
                    for (int r = 0; r < 4; ++r) { pv[r] = __expf(beta * d[r]); s2 += pv[r]; }
                } else {
                    int kb = kt*16 + lg*4;
                    #pragma unroll
                    for (int r = 0; r < 4; ++r) {
                        pv[r] = (kb + r <= qa) ? __expf(beta * d[r]) : 0.f; s2 += pv[r];
                    }
                }
                pk[tt][0] = pack2bf(pv[0], pv[1]); pk[tt][1] = pack2bf(pv[2], pv[3]);
            }
            // redistribute P^T into PV B-fragment: lane needs k = ch*32 + lg*8 + j
            union { bf16x8 v; u32 u[4]; } pf;
            #pragma unroll
            for (int w = 0; w < 4; ++w) {
                int srcl = lr + ((((lg << 1) + (w >> 1)) & 3) << 4);
                u32 a0 = (u32)__shfl((int)pk[0][w & 1], srcl);
                u32 a1 = (u32)__shfl((int)pk[1][w & 1], srcl);
                pf.u[w] = (lg >= 2) ? a1 : a0;
            }
            #pragma unroll
            for (int dc = 0; dc < 4; ++dc) {
                bf16x8 vf = *(const bf16x8*)&V[(size_t)(dc*16 + lr)*2048 + ch*32 + lg*8];
                o[dc] = mfma16(vf, pf.v, o[dc]);
            }
        }
        s2 += __shfl_xor(s2, 16); s2 += __shfl_xor(s2, 32);
        float inv = 1.f / s2;

        size_t row = ((size_t)(b*2048 + qa))*1024 + h*64;
        #pragma unroll
        for (int dc = 0; dc < 4; ++dc) {
            short4v wv;
            #pragma unroll
            for (int r = 0; r < 4; ++r) wv[r] = f2bf(o[dc][r] * inv);
            *(short4v*)&AO[row + dc*16 + lg*4] = wv;
        }
    }
}

// ---------- launch ----------
extern "C" void kernel_launch(void* const* d_in, const int* in_sizes, int n_in,
                              void* d_out, int out_size, void* d_ws, size_t ws_size,
                              hipStream_t stream) {
    const float* x  = (const float*)d_in[0];
    const float* Wq = (const float*)d_in[1];
    const float* Wk = (const float*)d_in[2];
    const float* Wv = (const float*)d_in[3];
    const float* Wo = (const float*)d_in[4];
    const float* bo = (const float*)d_in[5];
    float* out = (float*)d_out;
    short* ws = (short*)d_ws;

    short* xb  = ws;              // [4096][1024] bf16 x
    short* wqb = ws + 4194304;
    short* wkb = ws + 5242880;
    short* wvb = ws + 6291456;
    short* wob = ws + 7340032;
    short* Qh  = ws + 8388608;    // [2][16][2048][64], scaled by 0.125
    short* Kh  = ws + 12582912;   // [2][16][2048][64]
    short* Vt  = ws + 16777216;   // [2][16][64][2048]
    short* AO  = ws + 20971520;   // [4096][1024] attention output

    cvt_all_kernel<<<8192, 256, 0, stream>>>(x, Wq, Wk, Wv, Wo, ws);
    gemm_qkv_kernel<<<dim3(24, 32), 256, 0, stream>>>(xb, wqb, wkb, wvb, Qh, Kh, Vt);
    attn_kernel<<<512, 256, 0, stream>>>(Qh, Kh, Vt, AO);
    gemm_out_kernel<<<dim3(8, 32), 256, 0, stream>>>(AO, wob, bo, out);
}

// Round 3
// 275.890 us; speedup vs baseline: 1.0103x; 1.0103x over previous
//
#include <hip/hip_runtime.h>
#include <hip/hip_bf16.h>

typedef __attribute__((ext_vector_type(8))) short bf16x8;
typedef __attribute__((ext_vector_type(4))) short short4v;
typedef __attribute__((ext_vector_type(4))) float f32x4;
typedef unsigned int u32;

// ---------- helpers ----------
__device__ __forceinline__ short f2bf(float f) {
    union { float f; u32 i; } c; c.f = f;
    u32 r = c.i + 0x7FFFu + ((c.i >> 16) & 1u);   // RNE
    return (short)(r >> 16);
}
__device__ __forceinline__ u32 pack2bf(float lo, float hi) {
    return ((u32)(unsigned short)f2bf(hi) << 16) | (u32)(unsigned short)f2bf(lo);
}
__device__ __forceinline__ f32x4 mfma16(bf16x8 a, bf16x8 b, f32x4 c) {
    return __builtin_amdgcn_mfma_f32_16x16x32_bf16(a, b, c, 0, 0, 0);
}
__device__ __forceinline__ void load_lds16(const void* g, void* l) {
    __builtin_amdgcn_global_load_lds(
        (const __attribute__((address_space(1))) u32*)g,
        (__attribute__((address_space(3))) u32*)l, 16, 0, 0);
}

// ---------- fp32 -> bf16 convert (x + 4 weights fused) ----------
__global__ __launch_bounds__(256) void cvt_all_kernel(
    const float* __restrict__ x, const float* __restrict__ wq,
    const float* __restrict__ wk, const float* __restrict__ wv,
    const float* __restrict__ wo, short* __restrict__ ws) {
    const int XV = (4096 * 1024) / 4;   // float4 count for x
    const int WV = (1024 * 1024) / 4;   // float4 count per weight
    int i = blockIdx.x * 256 + threadIdx.x;
    const float4* src; short4v* dst; int off;
    if (i < XV)            { src = (const float4*)x;  dst = (short4v*)(ws);           off = i; }
    else if (i < XV + WV)  { src = (const float4*)wq; dst = (short4v*)(ws + 4194304); off = i - XV; }
    else if (i < XV + 2*WV){ src = (const float4*)wk; dst = (short4v*)(ws + 5242880); off = i - XV - WV; }
    else if (i < XV + 3*WV){ src = (const float4*)wv; dst = (short4v*)(ws + 6291456); off = i - XV - 2*WV; }
    else                   { src = (const float4*)wo; dst = (short4v*)(ws + 7340032); off = i - XV - 3*WV; }
    float4 v = src[off];
    short4v o;
    o.x = f2bf(v.x); o.y = f2bf(v.y); o.z = f2bf(v.z); o.w = f2bf(v.w);
    dst[off] = o;
}

// ---------- shared GEMM mainloop: C[128x128] += A[128xK] * B[128xK]^T ----------
__device__ __forceinline__ void gemm_mainloop(
    const short* __restrict__ A, const short* __restrict__ Bm,
    short* lds, int mbase, int nbase, int wave, int lane, f32x4 acc[4][4]) {
    const int K = 1024;
    const int lr = lane & 15, lg = lane >> 4;
    const int wm = wave >> 1, wn = wave & 1;
    for (int k0 = 0; k0 < K; k0 += 64) {
        __syncthreads();
        #pragma unroll
        for (int issue = 0; issue < 4; ++issue) {
            int f = issue * 4 + wave;
            int mt = f >> 1, kc = f & 1;
            load_lds16(A  + (size_t)(mbase + mt*16 + lr)*K + (k0 + kc*32 + lg*8), lds + f*512);
            load_lds16(Bm + (size_t)(nbase + mt*16 + lr)*K + (k0 + kc*32 + lg*8), lds + 8192 + f*512);
        }
        __syncthreads();
        #pragma unroll
        for (int kc = 0; kc < 2; ++kc) {
            bf16x8 af[4], bfv[4];
            #pragma unroll
            for (int mi = 0; mi < 4; ++mi)
                af[mi] = *(const bf16x8*)(lds + ((wm*4 + mi)*2 + kc)*512 + lane*8);
            #pragma unroll
            for (int ni = 0; ni < 4; ++ni)
                bfv[ni] = *(const bf16x8*)(lds + 8192 + ((wn*4 + ni)*2 + kc)*512 + lane*8);
            #pragma unroll
            for (int mi = 0; mi < 4; ++mi)
                #pragma unroll
                for (int ni = 0; ni < 4; ++ni)
                    acc[mi][ni] = mfma16(af[mi], bfv[ni], acc[mi][ni]);
        }
    }
}

// ---------- fused QKV projection ----------
__global__ __launch_bounds__(256) void gemm_qkv_kernel(
    const short* __restrict__ xb, const short* __restrict__ wqb,
    const short* __restrict__ wkb, const short* __restrict__ wvb,
    short* __restrict__ Qh, short* __restrict__ Kh, short* __restrict__ Vt) {
    __shared__ short lds[16384];
    const int wave = threadIdx.x >> 6, lane = threadIdx.x & 63;
    const int lr = lane & 15, lg = lane >> 4;
    const int sel = blockIdx.x >> 3;
    const int nbase = (blockIdx.x & 7) * 128;
    const int mbase = blockIdx.y * 128;
    const short* Bm = (sel == 0) ? wqb : (sel == 1) ? wkb : wvb;

    f32x4 acc[4][4];
    #pragma unroll
    for (int i = 0; i < 4; ++i)
        #pragma unroll
        for (int j = 0; j < 4; ++j) acc[i][j] = f32x4{0.f, 0.f, 0.f, 0.f};

    gemm_mainloop(xb, Bm, lds, mbase, nbase, wave, lane, acc);

    const int wm = wave >> 1, wn = wave & 1;
    #pragma unroll
    for (int mi = 0; mi < 4; ++mi) {
        int m0 = mbase + wm*64 + mi*16 + lg*4;
        #pragma unroll
        for (int ni = 0; ni < 4; ++ni) {
            int nc = nbase + wn*64 + ni*16 + lr;
            int h = nc >> 6, d = nc & 63;
            f32x4 v = acc[mi][ni];
            if (sel == 2) {
                int bi = m0 >> 11, np = m0 & 2047;
                short4v o;
                o.x = f2bf(v.x); o.y = f2bf(v.y); o.z = f2bf(v.z); o.w = f2bf(v.w);
                *(short4v*)&Vt[((size_t)(bi*16 + h)*64 + d)*2048 + np] = o;
            } else {
                short* dstb = (sel == 0) ? Qh : Kh;
                float sc = (sel == 0) ? 0.125f : 1.0f;
                #pragma unroll
                for (int r = 0; r < 4; ++r) {
                    int m = m0 + r; int bi = m >> 11, np = m & 2047;
                    dstb[((size_t)(bi*16 + h)*2048 + np)*64 + d] = f2bf(v[r] * sc);
                }
            }
        }
    }
}

// ---------- output projection ----------
__global__ __launch_bounds__(256) void gemm_out_kernel(
    const short* __restrict__ AO, const short* __restrict__ wob,
    const float* __restrict__ bias, float* __restrict__ out) {
    __shared__ short lds[16384];
    const int wave = threadIdx.x >> 6, lane = threadIdx.x & 63;
    const int lr = lane & 15, lg = lane >> 4;
    const int nbase = blockIdx.x * 128;
    const int mbase = blockIdx.y * 128;

    f32x4 acc[4][4];
    #pragma unroll
    for (int i = 0; i < 4; ++i)
        #pragma unroll
        for (int j = 0; j < 4; ++j) acc[i][j] = f32x4{0.f, 0.f, 0.f, 0.f};

    gemm_mainloop(AO, wob, lds, mbase, nbase, wave, lane, acc);

    const int wm = wave >> 1, wn = wave & 1;
    #pragma unroll
    for (int mi = 0; mi < 4; ++mi) {
        int m0 = mbase + wm*64 + mi*16 + lg*4;
        #pragma unroll
        for (int ni = 0; ni < 4; ++ni) {
            int nc = nbase + wn*64 + ni*16 + lr;
            float bj = bias[nc];
            f32x4 v = acc[mi][ni];
            #pragma unroll
            for (int r = 0; r < 4; ++r)
                out[(size_t)(m0 + r)*1024 + nc] = v[r] + bj;
        }
    }
}

// ---------- balanced flash-style 2-pass adaptive-temperature attention ----------
// Balanced wave-tasks (g=p then 127-p) + XCD-affine block swizzle (all 16
// blocks of one bh land on one XCD -> its K/V/Q fit that XCD's 4MB L2) +
// depth-2 register prefetch (A/B buffers, unroll-by-2) so L2-hit latency is
// hidden under the previous chunk's MFMA+exp work.
__global__ __launch_bounds__(256) void attn_kernel(
    const short* __restrict__ Qh, const short* __restrict__ Kh,
    const short* __restrict__ Vt, short* __restrict__ AO) {
    const int lane = threadIdx.x & 63;
    const int wave = threadIdx.x >> 6;
    // XCD-affine decode: bid = slot*8 + xcd; bh = (slot>>4)*8 + xcd (4 bh/XCD)
    const int bid  = blockIdx.x;             // 0..511
    const int xcd  = bid & 7;
    const int slot = bid >> 3;               // 0..63
    const int bh   = ((slot >> 4) << 3) | xcd;
    const int p    = (slot & 15) * 4 + wave; // 0..63
    const int lr = lane & 15, lg = lane >> 4;
    const short* Q = Qh + (size_t)bh * (2048 * 64);
    const short* K = Kh + (size_t)bh * (2048 * 64);
    const short* V = Vt + (size_t)bh * (64 * 2048);
    const int b = bh >> 4, h = bh & 15;

    #pragma unroll 1
    for (int gi = 0; gi < 2; ++gi) {
        const int g  = gi ? (127 - p) : p;   // 16-row q-group index
        const int qa = g * 16 + lr;

        bf16x8 qf0 = *(const bf16x8*)&Q[(size_t)qa*64 + lg*8];
        bf16x8 qf1 = *(const bf16x8*)&Q[(size_t)qa*64 + 32 + lg*8];

        // ================= pass 1: entropy stats =================
        float s = 0.f, t = 0.f;
        auto LD1 = [&](int kt, bf16x8& x0, bf16x8& x1) {
            const short* Kr = &K[(size_t)(kt*16 + lr)*64 + lg*8];
            x0 = *(const bf16x8*)Kr; x1 = *(const bf16x8*)(Kr + 32);
        };
        auto P1 = [&](bf16x8 kf0, bf16x8 kf1, int kt) {
            f32x4 d = {0.f,0.f,0.f,0.f};
            d = mfma16(kf0, qf0, d); d = mfma16(kf1, qf1, d);
            if (kt != g) {
                #pragma unroll
                for (int r = 0; r < 4; ++r) { float e = __expf(d[r]); s += e; t += e * d[r]; }
            } else {
                int kb = kt*16 + lg*4;
                #pragma unroll
                for (int r = 0; r < 4; ++r) {
                    float l = (kb + r <= qa) ? d[r] : -1e30f;
                    float e = __expf(l); s += e; t += e * l;
                }
            }
        };
        {
            bf16x8 A0, A1, B0, B1;
            LD1(0, A0, A1);
            if (g >= 1) LD1(1, B0, B1);
            int kt = 0;
            #pragma unroll 1
            for (; kt + 1 <= g; kt += 2) {
                P1(A0, A1, kt);
                if (kt + 2 <= g) LD1(kt + 2, A0, A1);
                P1(B0, B1, kt + 1);
                if (kt + 3 <= g) LD1(kt + 3, B0, B1);
            }
            if (kt <= g) P1(A0, A1, kt);
        }
        s += __shfl_xor(s, 16); t += __shfl_xor(t, 16);
        s += __shfl_xor(s, 32); t += __shfl_xor(t, 32);
        float H = __logf(s) - t / s;
        float beta = 1.f;
        if (H > 0.5f)
            beta = fmaxf((((-0.037f*H + 0.481f)*H - 2.3f)*H + 4.917f)*H - 1.791f, 1.f);

        // ================= pass 2: softmax(beta*l) and PV =================
        f32x4 o[4];
        #pragma unroll
        for (int dc = 0; dc < 4; ++dc) o[dc] = f32x4{0.f,0.f,0.f,0.f};
        float s2 = 0.f;
        const int nfull = g >> 1;            // chunks 0..nfull; chunk nfull masked
        auto LD2 = [&](int ch, bf16x8& c00, bf16x8& c01, bf16x8& c10, bf16x8& c11,
                       bf16x8& w0, bf16x8& w1, bf16x8& w2, bf16x8& w3) {
            const short* Kr0 = &K[(size_t)((ch*2)*16 + lr)*64 + lg*8];
            c00 = *(const bf16x8*)Kr0;          c01 = *(const bf16x8*)(Kr0 + 32);
            c10 = *(const bf16x8*)(Kr0 + 1024); c11 = *(const bf16x8*)(Kr0 + 1056);
            const short* Vr = &V[(size_t)lr*2048 + ch*32 + lg*8];
            w0 = *(const bf16x8*)Vr;
            w1 = *(const bf16x8*)(Vr + 16*2048);
            w2 = *(const bf16x8*)(Vr + 32*2048);
            w3 = *(const bf16x8*)(Vr + 48*2048);
        };
        auto P2 = [&](bf16x8 c00, bf16x8 c01, bf16x8 c10, bf16x8 c11,
                      bf16x8 w0, bf16x8 w1, bf16x8 w2, bf16x8 w3, int ch) {
            f32x4 d0 = {0.f,0.f,0.f,0.f}, d1 = {0.f,0.f,0.f,0.f};
            d0 = mfma16(c00, qf0, d0); d0 = mfma16(c01, qf1, d0);
            d1 = mfma16(c10, qf0, d1); d1 = mfma16(c11, qf1, d1);
            float p0[4], p1[4];
            if (ch != nfull) {
                #pragma unroll
                for (int r = 0; r < 4; ++r) {
                    p0[r] = __expf(beta * d0[r]); s2 += p0[r];
                    p1[r] = __expf(beta * d1[r]); s2 += p1[r];
                }
            } else {
                int kb0 = ch*32 + lg*4, kb1 = kb0 + 16;
                #pragma unroll
                for (int r = 0; r < 4; ++r) {
                    p0[r] = (kb0 + r <= qa) ? __expf(beta * d0[r]) : 0.f; s2 += p0[r];
                    p1[r] = (kb1 + r <= qa) ? __expf(beta * d1[r]) : 0.f; s2 += p1[r];
                }
            }
            u32 pk00 = pack2bf(p0[0], p0[1]), pk01 = pack2bf(p0[2], p0[3]);
            u32 pk10 = pack2bf(p1[0], p1[1]), pk11 = pack2bf(p1[2], p1[3]);
            union { bf16x8 v; u32 u[4]; } pf;
            #pragma unroll
            for (int w = 0; w < 4; ++w) {
                u32 x0 = (w & 1) ? pk01 : pk00;
                u32 x1 = (w & 1) ? pk11 : pk10;
                int srcl = lr + ((((lg << 1) + (w >> 1)) & 3) << 4);
                u32 a0 = (u32)__shfl((int)x0, srcl);
                u32 a1 = (u32)__shfl((int)x1, srcl);
                pf.u[w] = (lg >= 2) ? a1 : a0;
            }
            o[0] = mfma16(w0, pf.v, o[0]);
            o[1] = mfma16(w1, pf.v, o[1]);
            o[2] = mfma16(w2, pf.v, o[2]);
            o[3] = mfma16(w3, pf.v, o[3]);
        };
        {
            bf16x8 a00,a01,a10,a11, av0,av1,av2,av3;
            bf16x8 b00,b01,b10,b11, bv0,bv1,bv2,bv3;
            LD2(0, a00,a01,a10,a11, av0,av1,av2,av3);
            if (nfull >= 1) LD2(1, b00,b01,b10,b11, bv0,bv1,bv2,bv3);
            int ch = 0;
            #pragma unroll 1
            for (; ch + 1 <= nfull; ch += 2) {
                P2(a00,a01,a10,a11, av0,av1,av2,av3, ch);
                if (ch + 2 <= nfull) LD2(ch + 2, a00,a01,a10,a11, av0,av1,av2,av3);
                P2(b00,b01,b10,b11, bv0,bv1,bv2,bv3, ch + 1);
                if (ch + 3 <= nfull) LD2(ch + 3, b00,b01,b10,b11, bv0,bv1,bv2,bv3);
            }
            if (ch <= nfull) P2(a00,a01,a10,a11, av0,av1,av2,av3, ch);
        }
        s2 += __shfl_xor(s2, 16); s2 += __shfl_xor(s2, 32);
        float inv = 1.f / s2;

        size_t row = ((size_t)(b*2048 + qa))*1024 + h*64;
        #pragma unroll
        for (int dc = 0; dc < 4; ++dc) {
            short4v wv;
            #pragma unroll
            for (int r = 0; r < 4; ++r) wv[r] = f2bf(o[dc][r] * inv);
            *(short4v*)&AO[row + dc*16 + lg*4] = wv;
        }
    }
}

// ---------- launch ----------
extern "C" void kernel_launch(void* const* d_in, const int* in_sizes, int n_in,
                              void* d_out, int out_size, void* d_ws, size_t ws_size,
                              hipStream_t stream) {
    const float* x  = (const float*)d_in[0];
    const float* Wq = (const float*)d_in[1];
    const float* Wk = (const float*)d_in[2];
    const float* Wv = (const float*)d_in[3];
    const float* Wo = (const float*)d_in[4];
    const float* bo = (const float*)d_in[5];
    float* out = (float*)d_out;
    short* ws = (short*)d_ws;

    short* xb  = ws;              // [4096][1024] bf16 x
    short* wqb = ws + 4194304;
    short* wkb = ws + 5242880;
    short* wvb = ws + 6291456;
    short* wob = ws + 7340032;
    short* Qh  = ws + 8388608;    // [2][16][2048][64], scaled by 0.125
    short* Kh  = ws + 12582912;   // [2][16][2048][64]
    short* Vt  = ws + 16777216;   // [2][16][64][2048]
    short* AO  = ws + 20971520;   // [4096][1024] attention output

    cvt_all_kernel<<<8192, 256, 0, stream>>>(x, Wq, Wk, Wv, Wo, ws);
    gemm_qkv_kernel<<<dim3(24, 32), 256, 0, stream>>>(xb, wqb, wkb, wvb, Qh, Kh, Vt);
    attn_kernel<<<512, 256, 0, stream>>>(Qh, Kh, Vt, AO);
    gemm_out_kernel<<<dim3(8, 32), 256, 0, stream>>>(AO, wob, bo, out);
}